// Round 9
// baseline (605.963 us; speedup 1.0000x reference)
//
#include <hip/hip_runtime.h>

#define TOKS 49
#define DIM_ 384
#define NHEAD 12

typedef short bf16x8 __attribute__((ext_vector_type(8)));
typedef float f32x4 __attribute__((ext_vector_type(4)));

#define SXA 392   // xA / Ob: 64 x 392
#define SQK 136   // Q4 / K4: 64 x 136
#define SV   72   // Vt4:    128 x 72

#define LDS_ELEMS (64*SXA + 64*SQK + 64*SQK + 128*SV + 64*SXA)
#define LDS_BYTES (LDS_ELEMS*2)   // 153600 <= 163840

#define W1E (3*DIM_*DIM_)
#define W2E (DIM_*DIM_)
#define CMBE (64*NHEAD*64*64)
#define WS_NEEDED ((size_t)(W1E+W2E)*2 + (size_t)CMBE*4)

__device__ __forceinline__ unsigned short f2b(float f) {
  union { float f; unsigned u; } x; x.f = f;
  return (unsigned short)((x.u + 0x7FFFu + ((x.u >> 16) & 1u)) >> 16);  // RNE
}

// packed bf16 pair from two floats; lo -> bits[15:0] (lower address)
__device__ __forceinline__ unsigned pack2(float lo, float hi) {
  return (unsigned)f2b(lo) | ((unsigned)f2b(hi) << 16);
}

// w1p/w2p: fragment-major bf16: frag (ct,kk): lane l, elem j <-
//   W[ct*16 + (l&15)][kk*32 + (l>>4)*8 + j]  (one frag = coalesced 1KB)
// cmb[wi][h][q][k] (64x64 padded): bias[h][q][k] + mask[wi][q][k], -1e30 pad.
__global__ void prep_kernel(const float* __restrict__ qkv_w,
                            const float* __restrict__ proj_w,
                            const float* __restrict__ rpb,
                            const float* __restrict__ mask,
                            unsigned short* __restrict__ w1p,
                            unsigned short* __restrict__ w2p,
                            float* __restrict__ cmb) {
  int i = blockIdx.x * 256 + threadIdx.x;
  if (i < W1E) {
    int j = i & 7, l = (i >> 3) & 63, rest = i >> 9;
    int kk = rest % 12, ct = rest / 12;
    w1p[i] = f2b(qkv_w[(ct*16 + (l & 15))*DIM_ + kk*32 + ((l >> 4) << 3) + j]);
  }
  if (i < W2E) {
    int j = i & 7, l = (i >> 3) & 63, rest = i >> 9;
    int kk = rest % 12, ct = rest / 12;
    w2p[i] = f2b(proj_w[(ct*16 + (l & 15))*DIM_ + kk*32 + ((l >> 4) << 3) + j]);
  }
  if (i < CMBE) {
    int k = i & 63, q = (i >> 6) & 63, hw = i >> 12;
    int h = hw % 12, wi = hw / 12;
    float v = -1e30f;
    if (q < TOKS && k < TOKS) {
      int idx = (q/7 - k/7 + 6)*13 + (q%7 - k%7 + 6);
      v = rpb[idx*NHEAD + h] + mask[((size_t)wi*TOKS + q)*TOKS + k];
    }
    cmb[i] = v;
  }
}

__global__ __launch_bounds__(1024, 1)
void wattn_kernel(const float* __restrict__ x,
                  const unsigned short* __restrict__ w1p,
                  const float* __restrict__ b1,
                  const unsigned short* __restrict__ w2p,
                  const float* __restrict__ b2,
                  const float* __restrict__ cmb,
                  float* __restrict__ out) {
  extern __shared__ unsigned short lds[];
  unsigned short* xA  = lds;            // x tile bf16, rows 49..63 zeroed
  unsigned short* Q4  = xA + 64*SXA;    // q (scaled), 4 heads [tok][ch]
  unsigned short* K4  = Q4 + 64*SQK;    // k, 4 heads [tok][ch]
  unsigned short* Vt4 = K4 + 64*SQK;    // v transposed [ch][tok]
  unsigned short* Ob  = Vt4 + 128*SV;   // attn out [tok][12*32]

  const int tid  = threadIdx.x;
  const int lane = tid & 63;
  const int wv   = tid >> 6;            // 0..15
  const int lr   = lane & 15;
  const int lg   = lane >> 4;
  const int b    = blockIdx.x;
  const int wi   = b & 63;

  const int mh    = wv & 1;
  const int ctile = wv >> 1;            // 0..7

  // ---- stage x -> bf16 LDS
  {
    const float* xg = x + (size_t)b * TOKS * DIM_;
    for (int idx = tid; idx < TOKS*48; idx += 1024) {
      int r = idx / 48, c8 = (idx % 48) << 3;
      const float4* p = (const float4*)(xg + r*DIM_ + c8);
      float4 a0 = p[0], a1 = p[1];
      uint4 w;
      w.x = pack2(a0.x, a0.y); w.y = pack2(a0.z, a0.w);
      w.z = pack2(a1.x, a1.y); w.w = pack2(a1.z, a1.w);
      *(uint4*)&xA[r*SXA + c8] = w;
    }
    uint4 z = {0,0,0,0};
    for (int idx = tid; idx < 15*48; idx += 1024) {
      int r = 49 + idx / 48, c8 = (idx % 48) << 3;
      *(uint4*)&xA[r*SXA + c8] = z;
    }
  }
  __syncthreads();

  const f32x4 fz = {0.f, 0.f, 0.f, 0.f};
  f32x4 aq[2], ak[2], av[2];

  // GEMM1 compute for group gg (register accumulators only; q,k swapped ->
  // D[ch][tok]; v normal -> D[tok][ch])
  auto g1c = [&](int gg) {
    const int cb = gg*8 + ctile;
    const unsigned short* bq = w1p + (size_t)(cb*12)*512 + (lane << 3);
    const unsigned short* bk = bq + (size_t)(24*12)*512;
    const unsigned short* bv = bq + (size_t)(48*12)*512;
    #pragma unroll
    for (int t = 0; t < 2; ++t) { aq[t] = fz; ak[t] = fz; av[t] = fz; }
    #pragma unroll
    for (int kk = 0; kk < 12; ++kk) {
      bf16x8 fq = *(const bf16x8*)(bq + kk*512);
      bf16x8 fk = *(const bf16x8*)(bk + kk*512);
      bf16x8 fv = *(const bf16x8*)(bv + kk*512);
      #pragma unroll
      for (int t = 0; t < 2; ++t) {
        bf16x8 a = *(const bf16x8*)&xA[((mh*2 + t)*16 + lr)*SXA + kk*32 + lg*8];
        aq[t] = __builtin_amdgcn_mfma_f32_16x16x32_bf16(fq, a, aq[t], 0, 0, 0);
        ak[t] = __builtin_amdgcn_mfma_f32_16x16x32_bf16(fk, a, ak[t], 0, 0, 0);
        av[t] = __builtin_amdgcn_mfma_f32_16x16x32_bf16(a, fv, av[t], 0, 0, 0);
      }
    }
  };

  // GEMM1 epilogue: bias + pack + b64 LDS writes
  auto g1w = [&](int gg) {
    const int cb = gg*8 + ctile;
    const f32x4 qb4 = *(const f32x4*)(b1 + cb*16 + (lg << 2));
    const f32x4 kb4 = *(const f32x4*)(b1 + (24 + cb)*16 + (lg << 2));
    const float bsv = b1[(48 + cb)*16 + lr];
    const int d128 = (ctile << 4) + lr;
    #pragma unroll
    for (int t = 0; t < 2; ++t) {
      const int tokr = mh*32 + t*16 + lr;
      uint2 qw, kw, vw;
      qw.x = pack2((aq[t][0] + qb4[0]) * 0.17677669529663687f,
                   (aq[t][1] + qb4[1]) * 0.17677669529663687f);
      qw.y = pack2((aq[t][2] + qb4[2]) * 0.17677669529663687f,
                   (aq[t][3] + qb4[3]) * 0.17677669529663687f);
      kw.x = pack2(ak[t][0] + kb4[0], ak[t][1] + kb4[1]);
      kw.y = pack2(ak[t][2] + kb4[2], ak[t][3] + kb4[3]);
      vw.x = pack2(av[t][0] + bsv, av[t][1] + bsv);
      vw.y = pack2(av[t][2] + bsv, av[t][3] + bsv);
      *(uint2*)&Q4[tokr*SQK + (ctile << 4) + (lg << 2)] = qw;
      *(uint2*)&K4[tokr*SQK + (ctile << 4) + (lg << 2)] = kw;
      *(uint2*)&Vt4[d128*SV + mh*32 + t*16 + (lg << 2)] = vw;
    }
  };

  for (int g = 0; g < 3; ++g) {
    // ---- GEMM1 for this group (sequential; no cross-phase register carry)
    g1c(g);
    g1w(g);
    __syncthreads();

    // ---- attention: 16 tasks = (head hl, q-block m0), one per wave.
    const int hl = wv >> 2;
    const int h  = g*4 + hl;
    const int qoff = hl * 32;
    const int m0 = (wv & 3) << 4;

    // bias+mask loads (vectorized, independent of QK^T)
    f32x4 c4[4];
    const float* cp = cmb + (((size_t)(wi*NHEAD + h)) << 12) + ((m0 + lr) << 6);
    #pragma unroll
    for (int nt = 0; nt < 4; ++nt)
      c4[nt] = *(const f32x4*)(cp + nt*16 + (lg << 2));

    // swapped QK^T: S[k][q]; lane holds 16 k's (over nt) of column q=m0+lr
    bf16x8 qa = *(const bf16x8*)&Q4[(m0 + lr)*SQK + qoff + lg*8];
    f32x4 S[4];
    #pragma unroll
    for (int nt = 0; nt < 4; ++nt) {
      bf16x8 kb = *(const bf16x8*)&K4[((nt << 4) + lr)*SQK + qoff + lg*8];
      S[nt] = __builtin_amdgcn_mfma_f32_16x16x32_bf16(kb, qa, fz, 0, 0, 0);
    }

    // in-register softmax over k
    float p[4][4];
    float mx = -1e30f;
    #pragma unroll
    for (int nt = 0; nt < 4; ++nt)
      #pragma unroll
      for (int jj = 0; jj < 4; ++jj) {
        p[nt][jj] = S[nt][jj] + c4[nt][jj];
        mx = fmaxf(mx, p[nt][jj]);
      }
    mx = fmaxf(mx, __shfl_xor(mx, 16));
    mx = fmaxf(mx, __shfl_xor(mx, 32));
    float sum = 0.f;
    #pragma unroll
    for (int nt = 0; nt < 4; ++nt)
      #pragma unroll
      for (int jj = 0; jj < 4; ++jj) {
        float e = __expf(p[nt][jj] - mx);
        p[nt][jj] = e; sum += e;
      }
    sum += __shfl_xor(sum, 16);
    sum += __shfl_xor(sum, 32);
    const float inv = 1.0f / sum;

    unsigned pk0[4], pk1[4];
    #pragma unroll
    for (int nt = 0; nt < 4; ++nt) {
      pk0[nt] = pack2(p[nt][0]*inv, p[nt][1]*inv);
      pk1[nt] = pack2(p[nt][2]*inv, p[nt][3]*inv);
    }

    // PV (swapped): O^T[d][q] = mfma(A=Vt, B=P^T); af built by shuffles
    const int src0 = lr + ((lane & 16) << 1);
    const int src1 = src0 + 16;
    const bool loH = lane < 32;
    f32x4 o0 = fz, o1 = fz;
    #pragma unroll
    for (int kk = 0; kk < 2; ++kk) {
      unsigned wA0 = __shfl(pk0[2*kk], src0), wB0 = __shfl(pk0[2*kk+1], src0);
      unsigned wA1 = __shfl(pk1[2*kk], src0), wB1 = __shfl(pk1[2*kk+1], src0);
      unsigned wA2 = __shfl(pk0[2*kk], src1), wB2 = __shfl(pk0[2*kk+1], src1);
      unsigned wA3 = __shfl(pk1[2*kk], src1), wB3 = __shfl(pk1[2*kk+1], src1);
      union { unsigned u[4]; bf16x8 v; } af;
      af.u[0] = loH ? wA0 : wB0;
      af.u[1] = loH ? wA1 : wB1;
      af.u[2] = loH ? wA2 : wB2;
      af.u[3] = loH ? wA3 : wB3;
      bf16x8 vb0 = *(const bf16x8*)&Vt4[(qoff + lr)*SV + kk*32 + lg*8];
      bf16x8 vb1 = *(const bf16x8*)&Vt4[(qoff + 16 + lr)*SV + kk*32 + lg*8];
      o0 = __builtin_amdgcn_mfma_f32_16x16x32_bf16(vb0, af.v, o0, 0, 0, 0);
      o1 = __builtin_amdgcn_mfma_f32_16x16x32_bf16(vb1, af.v, o1, 0, 0, 0);
    }
    const int orow = m0 + lr;
    uint2 w0, w1;
    w0.x = pack2(o0[0], o0[1]); w0.y = pack2(o0[2], o0[3]);
    w1.x = pack2(o1[0], o1[1]); w1.y = pack2(o1[2], o1[3]);
    *(uint2*)&Ob[orow*SXA + h*32 + (lg << 2)]      = w0;
    *(uint2*)&Ob[orow*SXA + h*32 + 16 + (lg << 2)] = w1;

    __syncthreads();
  }

  // ---- GEMM2 (swapped): out^T[ch][tok] -> dwordx4 global stores
  {
    const unsigned short* bp0 = w2p + (size_t)(ctile*12)*512 + (lane << 3);
    const unsigned short* bp1 = bp0 + (size_t)(8*12)*512;
    const unsigned short* bp2 = bp0 + (size_t)(16*12)*512;
    f32x4 ac0[2], ac1[2], ac2[2];
    #pragma unroll
    for (int t = 0; t < 2; ++t) { ac0[t] = fz; ac1[t] = fz; ac2[t] = fz; }
    #pragma unroll
    for (int kk = 0; kk < 12; ++kk) {
      bf16x8 f0 = *(const bf16x8*)(bp0 + kk*512);
      bf16x8 f1 = *(const bf16x8*)(bp1 + kk*512);
      bf16x8 f2 = *(const bf16x8*)(bp2 + kk*512);
      #pragma unroll
      for (int t = 0; t < 2; ++t) {
        bf16x8 ob = *(const bf16x8*)&Ob[((mh*2 + t)*16 + lr)*SXA + kk*32 + lg*8];
        ac0[t] = __builtin_amdgcn_mfma_f32_16x16x32_bf16(f0, ob, ac0[t], 0, 0, 0);
        ac1[t] = __builtin_amdgcn_mfma_f32_16x16x32_bf16(f1, ob, ac1[t], 0, 0, 0);
        ac2[t] = __builtin_amdgcn_mfma_f32_16x16x32_bf16(f2, ob, ac2[t], 0, 0, 0);
      }
    }
    float* og = out + (size_t)b * TOKS * DIM_;
    #pragma unroll
    for (int ni = 0; ni < 3; ++ni) {
      const int col0 = ((ctile + ni*8) << 4) + (lg << 2);
      const f32x4 pb = *(const f32x4*)(b2 + col0);
      const f32x4* ac = ni == 0 ? ac0 : (ni == 1 ? ac1 : ac2);
      #pragma unroll
      for (int t = 0; t < 2; ++t) {
        const int tok = (mh*2 + t)*16 + lr;
        if (tok < TOKS) {
          f32x4 v = ac[t] + pb;
          *(f32x4*)(og + tok*DIM_ + col0) = v;
        }
      }
    }
  }
}

extern "C" void kernel_launch(void* const* d_in, const int* in_sizes, int n_in,
                              void* d_out, int out_size, void* d_ws, size_t ws_size,
                              hipStream_t stream) {
  const float* x      = (const float*)d_in[0];
  const float* mask   = (const float*)d_in[1];
  const float* qkv_w  = (const float*)d_in[2];
  const float* qkv_b  = (const float*)d_in[3];
  const float* proj_w = (const float*)d_in[4];
  const float* proj_b = (const float*)d_in[5];
  const float* rpb    = (const float*)d_in[6];
  float* out = (float*)d_out;

  if (ws_size < WS_NEEDED) return;  // refuse to fault on undersized workspace

  unsigned short* w1p = (unsigned short*)d_ws;
  unsigned short* w2p = w1p + W1E;
  float* cmb = (float*)(w2p + W2E);

  prep_kernel<<<(CMBE + 255)/256, 256, 0, stream>>>(qkv_w, proj_w, rpb, mask,
                                                    w1p, w2p, cmb);

  hipFuncSetAttribute((const void*)wattn_kernel,
                      hipFuncAttributeMaxDynamicSharedMemorySize, LDS_BYTES);
  wattn_kernel<<<4096, 1024, LDS_BYTES, stream>>>(x, w1p, qkv_b, w2p,
                                                  proj_b, cmb, out);
}